// Round 6
// baseline (96.769 us; speedup 1.0000x reference)
//
#include <hip/hip_runtime.h>

// Problem constants (match the reference).
constexpr int B = 32, C = 256, H = 56, W = 56, K = 4;
constexpr int HW = H * W;                 // 3136 floats per (b,c) plane
constexpr int BC = B * C;                 // 8192 planes
constexpr long long IMG = (long long)BC * HW;  // 25,690,112 elements

// Native clang vector type — accepted by __builtin_nontemporal_store.
typedef float f4 __attribute__((ext_vector_type(4)));

// One block per TWO consecutive planes (grid = 4096, 256 threads).
// ALL 24 main loads (+8 predicated tail loads) are issued BEFORE any
// consume/store — max per-wave MLP (~32 outstanding vmem ops/thread).
__global__ __launch_bounds__(256) void sk_fuse_kernel(
    const float* __restrict__ x0, const float* __restrict__ x1,
    const float* __restrict__ x2, const float* __restrict__ x3,
    const float* __restrict__ logits,        // [K, B, C] = [K, BC]
    float* __restrict__ out,                 // [B, C, H, W]
    float* __restrict__ s_out,               // [B, C]
    float* __restrict__ usum_out)            // [B, C]
{
    const int tid = threadIdx.x;
    const int bcA = blockIdx.x * 2;
    const int bcB = bcA + 1;

    const size_t baseA = (size_t)bcA * HW;
    const size_t baseB = (size_t)bcB * HW;

    const f4* __restrict__ pA0 = (const f4*)(x0 + baseA);
    const f4* __restrict__ pA1 = (const f4*)(x1 + baseA);
    const f4* __restrict__ pA2 = (const f4*)(x2 + baseA);
    const f4* __restrict__ pA3 = (const f4*)(x3 + baseA);
    const f4* __restrict__ pB0 = (const f4*)(x0 + baseB);
    const f4* __restrict__ pB1 = (const f4*)(x1 + baseB);
    const f4* __restrict__ pB2 = (const f4*)(x2 + baseB);
    const f4* __restrict__ pB3 = (const f4*)(x3 + baseB);
    f4* __restrict__ poA = (f4*)(out + baseA);
    f4* __restrict__ poB = (f4*)(out + baseB);

    const int i0 = tid, i1 = tid + 256, i2 = tid + 512;
    const bool tail = (tid < 16);
    const int i3 = 768 + (tid & 15);

    // ==================== issue ALL loads up front ====================
    const f4 A00 = pA0[i0], A01 = pA1[i0], A02 = pA2[i0], A03 = pA3[i0];
    const f4 A10 = pA0[i1], A11 = pA1[i1], A12 = pA2[i1], A13 = pA3[i1];
    const f4 A20 = pA0[i2], A21 = pA1[i2], A22 = pA2[i2], A23 = pA3[i2];
    const f4 B00 = pB0[i0], B01 = pB1[i0], B02 = pB2[i0], B03 = pB3[i0];
    const f4 B10 = pB0[i1], B11 = pB1[i1], B12 = pB2[i1], B13 = pB3[i1];
    const f4 B20 = pB0[i2], B21 = pB1[i2], B22 = pB2[i2], B23 = pB3[i2];

    f4 AT0 = 0.0f, AT1 = 0.0f, AT2 = 0.0f, AT3 = 0.0f;
    f4 BT0 = 0.0f, BT1 = 0.0f, BT2 = 0.0f, BT3 = 0.0f;
    if (tail) {
        AT0 = pA0[i3]; AT1 = pA1[i3]; AT2 = pA2[i3]; AT3 = pA3[i3];
        BT0 = pB0[i3]; BT1 = pB1[i3]; BT2 = pB2[i3]; BT3 = pB3[i3];
    }

    // ---- softmax weights (block-uniform scalar loads, issued last —
    //      they complete quickly and are needed first) ----
    auto softmax4 = [&](int bc, float& w0, float& w1, float& w2, float& w3) {
        const float l0 = logits[0 * BC + bc];
        const float l1 = logits[1 * BC + bc];
        const float l2 = logits[2 * BC + bc];
        const float l3 = logits[3 * BC + bc];
        const float m  = fmaxf(fmaxf(l0, l1), fmaxf(l2, l3));
        const float e0 = expf(l0 - m);
        const float e1 = expf(l1 - m);
        const float e2 = expf(l2 - m);
        const float e3 = expf(l3 - m);
        const float inv = 1.0f / (e0 + e1 + e2 + e3);
        w0 = e0 * inv; w1 = e1 * inv; w2 = e2 * inv; w3 = e3 * inv;
    };
    float wA0, wA1, wA2, wA3, wB0, wB1, wB2, wB3;
    softmax4(bcA, wA0, wA1, wA2, wA3);
    softmax4(bcB, wB0, wB1, wB2, wB3);

    float usumA = 0.0f, usumB = 0.0f;

    auto fuse = [](const f4& a, const f4& b, const f4& c, const f4& d,
                   float w0, float w1, float w2, float w3,
                   float& usum) -> f4 {
        f4 o;
        o.x = w0 * a.x + w1 * b.x + w2 * c.x + w3 * d.x;
        o.y = w0 * a.y + w1 * b.y + w2 * c.y + w3 * d.y;
        o.z = w0 * a.z + w1 * b.z + w2 * c.z + w3 * d.z;
        o.w = w0 * a.w + w1 * b.w + w2 * c.w + w3 * d.w;
        usum += (a.x + b.x + c.x + d.x)
              + (a.y + b.y + c.y + d.y)
              + (a.z + b.z + c.z + d.z)
              + (a.w + b.w + c.w + d.w);
        return o;
    };

    // ==================== consume in load order ====================
    __builtin_nontemporal_store(fuse(A00,A01,A02,A03,wA0,wA1,wA2,wA3,usumA), &poA[i0]);
    __builtin_nontemporal_store(fuse(A10,A11,A12,A13,wA0,wA1,wA2,wA3,usumA), &poA[i1]);
    __builtin_nontemporal_store(fuse(A20,A21,A22,A23,wA0,wA1,wA2,wA3,usumA), &poA[i2]);
    __builtin_nontemporal_store(fuse(B00,B01,B02,B03,wB0,wB1,wB2,wB3,usumB), &poB[i0]);
    __builtin_nontemporal_store(fuse(B10,B11,B12,B13,wB0,wB1,wB2,wB3,usumB), &poB[i1]);
    __builtin_nontemporal_store(fuse(B20,B21,B22,B23,wB0,wB1,wB2,wB3,usumB), &poB[i2]);
    if (tail) {
        __builtin_nontemporal_store(fuse(AT0,AT1,AT2,AT3,wA0,wA1,wA2,wA3,usumA), &poA[i3]);
        __builtin_nontemporal_store(fuse(BT0,BT1,BT2,BT3,wB0,wB1,wB2,wB3,usumB), &poB[i3]);
    }

    // ---- block reduction: wave shuffle then LDS across 4 waves ----
    #pragma unroll
    for (int off = 32; off > 0; off >>= 1) {
        usumA += __shfl_down(usumA, off, 64);
        usumB += __shfl_down(usumB, off, 64);
    }

    __shared__ float wsumA[4];
    __shared__ float wsumB[4];
    const int lane = tid & 63;
    const int wid  = tid >> 6;
    if (lane == 0) { wsumA[wid] = usumA; wsumB[wid] = usumB; }
    __syncthreads();
    if (tid == 0) {
        const float tA = wsumA[0] + wsumA[1] + wsumA[2] + wsumA[3];
        const float tB = wsumB[0] + wsumB[1] + wsumB[2] + wsumB[3];
        usum_out[bcA] = tA;
        usum_out[bcB] = tB;
        s_out[bcA]    = tA * (1.0f / HW);
        s_out[bcB]    = tB * (1.0f / HW);
    }
}

extern "C" void kernel_launch(void* const* d_in, const int* in_sizes, int n_in,
                              void* d_out, int out_size, void* d_ws, size_t ws_size,
                              hipStream_t stream) {
    const float* x0     = (const float*)d_in[0];
    const float* x1     = (const float*)d_in[1];
    const float* x2     = (const float*)d_in[2];
    const float* x3     = (const float*)d_in[3];
    const float* logits = (const float*)d_in[4];

    float* out      = (float*)d_out;          // [B,C,H,W]
    float* s_out    = out + IMG;              // [B,C]
    float* usum_out = s_out + BC;             // [B,C]

    sk_fuse_kernel<<<BC / 2, 256, 0, stream>>>(x0, x1, x2, x3, logits,
                                               out, s_out, usum_out);
}